// Round 3
// baseline (92.224 us; speedup 1.0000x reference)
//
#include <hip/hip_runtime.h>

// Problem constants (from reference)
#define B_  64
#define T_  288
#define V_  24
#define D_  256
#define TOD_DIM 128
#define DOW_DIM 32
#define DOM_DIM 32
#define DOY_DIM 64
#define BTPB 4   // (b,t) pairs per block; 4 | 288 so all 4 share the same b

typedef float f32x4 __attribute__((ext_vector_type(4)));  // native vec for nontemporal builtin

// One block per 4 consecutive (b,t). 256 threads.
// Phase 1: build pos[4][256] in LDS (dow/dom/doy composed once, tod per-t);
//          stage feats[4][24].
// Phase 2: 6 iterations; per iteration load W/b float4 once, store to 4 bt.
__global__ __launch_bounds__(256) void input_emb_kernel(
    const float* __restrict__ features,    // (B,T,V)
    const int*   __restrict__ bar_in_day,  // (B,T)
    const int*   __restrict__ day_of_week, // (B,)
    const int*   __restrict__ day_of_month,// (B,)
    const int*   __restrict__ day_of_year, // (B,)
    const float* __restrict__ W,           // (V,D)
    const float* __restrict__ bias,        // (V,D)
    const float* __restrict__ tod_table,   // (288,128)
    const float* __restrict__ dow_table,   // (7,32)
    const float* __restrict__ dom_table,   // (32,32)
    const float* __restrict__ doy_table,   // (367,64)
    float* __restrict__ out)               // (B,T,V,D)
{
    __shared__ __align__(16) float pos[BTPB][D_];
    __shared__ float feats[BTPB][V_];

    const int bt0 = blockIdx.x * BTPB;
    const int b   = bt0 / T_;          // all BTPB share this b (BTPB | T_)
    const int tid = threadIdx.x;

    // ---- Phase 1: compose positional vectors ----
    if (tid < TOD_DIM) {
        #pragma unroll
        for (int j = 0; j < BTPB; ++j)
            pos[j][tid] = tod_table[bar_in_day[bt0 + j] * TOD_DIM + tid];
    } else {
        float p;
        if (tid < TOD_DIM + DOW_DIM) {
            p = dow_table[day_of_week[b] * DOW_DIM + (tid - TOD_DIM)];
        } else if (tid < TOD_DIM + DOW_DIM + DOM_DIM) {
            p = dom_table[day_of_month[b] * DOM_DIM + (tid - TOD_DIM - DOW_DIM)];
        } else {
            p = doy_table[day_of_year[b] * DOY_DIM + (tid - TOD_DIM - DOW_DIM - DOM_DIM)];
        }
        #pragma unroll
        for (int j = 0; j < BTPB; ++j)
            pos[j][tid] = p;           // same value for all 4 t (per-b tables)
    }
    if (tid < BTPB * V_) {             // 96 feature scalars
        feats[tid / V_][tid % V_] = features[bt0 * V_ + tid];
    }
    __syncthreads();

    // ---- Phase 2: fan out to (4, V, D) ----
    const int d4 = tid & 63;           // float4 column, iteration-invariant
    const int q  = tid >> 6;           // wave index 0..3 (wave-uniform)

    f32x4 p4[BTPB];
    #pragma unroll
    for (int j = 0; j < BTPB; ++j)
        p4[j] = *reinterpret_cast<const f32x4*>(&pos[j][d4 << 2]);

    float* outbase = out + (size_t)bt0 * (V_ * D_);

    #pragma unroll
    for (int it = 0; it < V_ / 4; ++it) {      // 6 iterations
        const int v = it * 4 + q;              // wave-uniform variable index
        const f32x4 w4 = *reinterpret_cast<const f32x4*>(W    + (v << 8) + (d4 << 2));
        const f32x4 b4 = *reinterpret_cast<const f32x4*>(bias + (v << 8) + (d4 << 2));
        const int idx = (v << 6) + d4;         // float4 index within (V,D)

        #pragma unroll
        for (int j = 0; j < BTPB; ++j) {
            const float x = feats[j][v];
            f32x4 o;
            o.x = fmaf(x, w4.x, b4.x) + p4[j].x;
            o.y = fmaf(x, w4.y, b4.y) + p4[j].y;
            o.z = fmaf(x, w4.z, b4.z) + p4[j].z;
            o.w = fmaf(x, w4.w, b4.w) + p4[j].w;
            __builtin_nontemporal_store(o,
                reinterpret_cast<f32x4*>(outbase + (size_t)j * (V_ * D_) + (idx << 2)));
        }
    }
}

extern "C" void kernel_launch(void* const* d_in, const int* in_sizes, int n_in,
                              void* d_out, int out_size, void* d_ws, size_t ws_size,
                              hipStream_t stream) {
    const float* features     = (const float*)d_in[0];
    const int*   bar_in_day   = (const int*)d_in[1];
    const int*   day_of_week  = (const int*)d_in[2];
    const int*   day_of_month = (const int*)d_in[3];
    const int*   day_of_year  = (const int*)d_in[4];
    const float* W            = (const float*)d_in[5];
    const float* bias         = (const float*)d_in[6];
    const float* tod_table    = (const float*)d_in[7];
    const float* dow_table    = (const float*)d_in[8];
    const float* dom_table    = (const float*)d_in[9];
    const float* doy_table    = (const float*)d_in[10];
    float* out = (float*)d_out;

    dim3 grid((B_ * T_) / BTPB);   // 4608 blocks = 18 per CU
    dim3 block(256);
    input_emb_kernel<<<grid, block, 0, stream>>>(
        features, bar_in_day, day_of_week, day_of_month, day_of_year,
        W, bias, tod_table, dow_table, dom_table, doy_table, out);
}